// Round 1
// baseline (548.156 us; speedup 1.0000x reference)
//
#include <hip/hip_runtime.h>
#include <math.h>

#define NN   10000
#define EE   200000
#define RR   400000
#define FIN  128
#define FOUT 64

#define HASH_BITS 20
#define HSIZE (1u << HASH_BITS)
#define HMASK (HSIZE - 1u)

// ---- workspace layout (units of 4 bytes) ----
#define O_SUMS  0
#define O_CNTS  (O_SUMS + EE)          // 200000
#define O_S     (O_CNTS + EE)          // 200000
#define O_NUM   (O_S + NN)             // 10000
#define O_HKEY  (O_NUM + NN * FOUT)    // 640000
#define O_HPRIO (O_HKEY + HSIZE)       // 1048576
#define O_MEANS (O_HPRIO + HSIZE)      // 1048576
#define O_SEQ   (O_MEANS + EE)
#define O_DW    (O_SEQ + NN * FOUT)
#define WS_WORDS (O_DW + 2 * EE)
#define ZERO_WORDS O_MEANS             // [sums,cnts,S,Num,hkey,hprio] must be zeroed

// ---------------- seq_fts = x @ W^T ----------------
__global__ __launch_bounds__(256) void k_seqfts(const float* __restrict__ x,
                                                const float* __restrict__ W,
                                                float* __restrict__ seq) {
    __shared__ float Wt[FIN][FOUT + 1];   // transposed W, padded
    __shared__ float xs[FIN][16 + 1];     // transposed x tile (16 rows)
    int t = threadIdx.x;
    for (int e = t; e < FOUT * FIN; e += 256) {
        int c = e >> 7, k = e & 127;
        Wt[k][c] = W[e];
    }
    int row0 = blockIdx.x * 16;
    for (int e = t; e < 16 * FIN; e += 256) {
        int r = e >> 7, k = e & 127;
        int gr = row0 + r;
        xs[k][r] = (gr < NN) ? x[(size_t)gr * FIN + k] : 0.f;
    }
    __syncthreads();
    int col = t & 63;
    int rg  = t >> 6;   // wave id -> rows rg*4 .. rg*4+3
    float acc[4] = {0.f, 0.f, 0.f, 0.f};
    for (int k = 0; k < FIN; ++k) {
        float w = Wt[k][col];
        #pragma unroll
        for (int i = 0; i < 4; ++i) acc[i] += w * xs[k][rg * 4 + i];
    }
    #pragma unroll
    for (int i = 0; i < 4; ++i) {
        int gr = row0 + rg * 4 + i;
        if (gr < NN) seq[(size_t)gr * FOUT + col] = acc[i];
    }
}

// ---------------- fts_rel dot + segment sums ----------------
__global__ __launch_bounds__(256) void k_rel(const float* __restrict__ rel,
                                             const float* __restrict__ wrel,
                                             const int* __restrict__ rseg,
                                             float* __restrict__ sums,
                                             float* __restrict__ cnts) {
    int gid  = blockIdx.x * 256 + threadIdx.x;
    int row  = gid >> 5;     // one 32-lane group per relation row
    int lane = gid & 31;
    if (row >= RR) return;
    float4 v = *(const float4*)(rel + (size_t)row * FIN + lane * 4);
    float4 w = *(const float4*)(wrel + lane * 4);
    float s = v.x * w.x + v.y * w.y + v.z * w.z + v.w * w.w;
    #pragma unroll
    for (int off = 16; off >= 1; off >>= 1) s += __shfl_xor(s, off, 64);
    if (lane == 0) {
        int seg = rseg[row];
        atomicAdd(&sums[seg], s);
        atomicAdd(&cnts[seg], 1.0f);
    }
}

__global__ void k_means(const float* __restrict__ sums,
                        const float* __restrict__ cnts,
                        float* __restrict__ means) {
    int e = blockIdx.x * 256 + threadIdx.x;
    if (e < EE) means[e] = sums[e] / fmaxf(cnts[e], 1.0f);
}

// ---------------- scatter duplicate resolution ----------------
__device__ __forceinline__ unsigned hash_cell(unsigned cell) {
    return (cell * 2654435761u) >> (32 - HASH_BITS);
}

__device__ __forceinline__ void entry_ij(const int* ep, int e, int& i, int& j, int& k) {
    k = (e < EE) ? e : e - EE;
    int a = ep[2 * k], b = ep[2 * k + 1];
    if (e < EE) { i = a; j = b; } else { i = b; j = a; }
}

__global__ void k_scatA(const int* __restrict__ ep,
                        unsigned* __restrict__ hkey,
                        unsigned* __restrict__ hprio) {
    int e = blockIdx.x * 256 + threadIdx.x;
    if (e >= 2 * EE) return;
    int i, j, k;
    entry_ij(ep, e, i, j, k);
    unsigned cell = (unsigned)i * NN + (unsigned)j;
    unsigned keyv = cell + 1u;
    unsigned h = hash_cell(cell);
    while (true) {
        unsigned old = atomicCAS(&hkey[h], 0u, keyv);
        if (old == 0u || old == keyv) break;
        h = (h + 1u) & HMASK;
    }
    atomicMax(&hprio[h], (unsigned)(e + 1));
}

__global__ void k_scatB(const int* __restrict__ ep,
                        const float* __restrict__ means,
                        const unsigned* __restrict__ hkey,
                        const unsigned* __restrict__ hprio,
                        const float* __restrict__ adj,
                        float* __restrict__ S,
                        float* __restrict__ dwbuf) {
    int e = blockIdx.x * 256 + threadIdx.x;
    if (e >= 2 * EE) return;
    int i, j, k;
    entry_ij(ep, e, i, j, k);
    unsigned cell = (unsigned)i * NN + (unsigned)j;
    unsigned keyv = cell + 1u;
    unsigned h = hash_cell(cell);
    while (hkey[h] != keyv) h = (h + 1u) & HMASK;
    float dw = 0.f;
    if (hprio[h] == (unsigned)(e + 1)) {   // last-write-wins winner
        float v  = means[k];
        float sg = 1.f / (1.f + __expf(-v));
        float aij = adj[(size_t)i * NN + j];
        dw = __expf(aij + sg) - __expf(aij + 0.5f);
        if (dw != 0.f) atomicAdd(&S[i], dw);
    }
    dwbuf[e] = dw;
}

// one 64-lane wave per entry: Num[i,:] += dw * seq[j,:]
__global__ __launch_bounds__(256) void k_scatC(const int* __restrict__ ep,
                                               const float* __restrict__ dwbuf,
                                               const float* __restrict__ seq,
                                               float* __restrict__ Num) {
    int gid  = blockIdx.x * 256 + threadIdx.x;
    int e    = gid >> 6;
    int lane = gid & 63;
    if (e >= 2 * EE) return;
    float dw = dwbuf[e];
    if (dw == 0.f) return;
    int i, j, k;
    entry_ij(ep, e, i, j, k);
    atomicAdd(&Num[(size_t)i * FOUT + lane], dw * seq[(size_t)j * FOUT + lane]);
}

// ---------------- main: Num = exp(adj+0.5) @ seq, S = rowsum ----------------
#define BM 64
#define BK 64
#define KSPLIT 8
#define NCHUNK ((NN + BK - 1) / BK)   // 157

__global__ __launch_bounds__(256) void k_main(const float* __restrict__ adj,
                                              const float* __restrict__ seq,
                                              float* __restrict__ Num,
                                              float* __restrict__ S) {
    __shared__ float As[BM][BK + 4];     // [row][k], stride 68
    __shared__ float Bs[BK][FOUT + 4];   // [k][col], stride 68
    int t    = threadIdx.x;
    int row0 = blockIdx.x * BM;
    int cpk  = (NCHUNK + KSPLIT - 1) / KSPLIT;  // 20
    int c0   = blockIdx.y * cpk;
    int c1   = min(NCHUNK, c0 + cpk);
    int cg = t & 15;          // col group -> cols cg*4..cg*4+3
    int rg = t >> 4;          // row group -> rows rg*4..rg*4+3
    float acc[4][4] = {{0.f}};

    for (int ch = c0; ch < c1; ++ch) {
        int k0 = ch * BK;
        // stage A = exp(adj+0.5) with fused row-sum reduction
        #pragma unroll
        for (int e = 0; e < 4; ++e) {
            int idx4 = e * 256 + t;
            int r  = idx4 >> 4;
            int kk = (idx4 & 15) * 4;
            int gr = row0 + r, gk = k0 + kk;
            bool ok = (gr < NN) && (gk < NN);   // NN%4==0: float4 fully in/out
            float4 vv = make_float4(0.f, 0.f, 0.f, 0.f);
            if (ok) vv = *(const float4*)(adj + (size_t)gr * NN + gk);
            float w0 = ok ? __expf(vv.x + 0.5f) : 0.f;
            float w1 = ok ? __expf(vv.y + 0.5f) : 0.f;
            float w2 = ok ? __expf(vv.z + 0.5f) : 0.f;
            float w3 = ok ? __expf(vv.w + 0.5f) : 0.f;
            *(float4*)&As[r][kk] = make_float4(w0, w1, w2, w3);
            float p = w0 + w1 + w2 + w3;          // row partial
            p += __shfl_xor(p, 1, 64);
            p += __shfl_xor(p, 2, 64);
            p += __shfl_xor(p, 4, 64);
            p += __shfl_xor(p, 8, 64);
            if ((t & 15) == 0 && gr < NN) atomicAdd(&S[gr], p);
        }
        // stage B = seq rows k0..k0+63
        #pragma unroll
        for (int e = 0; e < 4; ++e) {
            int idx4 = e * 256 + t;
            int r  = idx4 >> 4;
            int cc = (idx4 & 15) * 4;
            int gk = k0 + r;
            float4 vv = make_float4(0.f, 0.f, 0.f, 0.f);
            if (gk < NN) vv = *(const float4*)(seq + (size_t)gk * FOUT + cc);
            *(float4*)&Bs[r][cc] = vv;
        }
        __syncthreads();
        #pragma unroll 8
        for (int k = 0; k < BK; ++k) {
            float a0 = As[rg * 4 + 0][k];
            float a1 = As[rg * 4 + 1][k];
            float a2 = As[rg * 4 + 2][k];
            float a3 = As[rg * 4 + 3][k];
            float4 b = *(const float4*)&Bs[k][cg * 4];
            acc[0][0] += a0 * b.x; acc[0][1] += a0 * b.y; acc[0][2] += a0 * b.z; acc[0][3] += a0 * b.w;
            acc[1][0] += a1 * b.x; acc[1][1] += a1 * b.y; acc[1][2] += a1 * b.z; acc[1][3] += a1 * b.w;
            acc[2][0] += a2 * b.x; acc[2][1] += a2 * b.y; acc[2][2] += a2 * b.z; acc[2][3] += a2 * b.w;
            acc[3][0] += a3 * b.x; acc[3][1] += a3 * b.y; acc[3][2] += a3 * b.z; acc[3][3] += a3 * b.w;
        }
        __syncthreads();
    }
    #pragma unroll
    for (int i = 0; i < 4; ++i) {
        int gr = row0 + rg * 4 + i;
        if (gr < NN) {
            #pragma unroll
            for (int j = 0; j < 4; ++j)
                atomicAdd(&Num[(size_t)gr * FOUT + cg * 4 + j], acc[i][j]);
        }
    }
}

// ---------------- finalize: elu(Num/S + bias) ----------------
__global__ void k_final(const float* __restrict__ Num,
                        const float* __restrict__ S,
                        const float* __restrict__ bias,
                        float* __restrict__ out) {
    int gid = blockIdx.x * 256 + threadIdx.x;
    if (gid >= NN * FOUT) return;
    int i = gid >> 6, c = gid & 63;
    float v = Num[gid] / S[i] + bias[c];
    out[gid] = (v > 0.f) ? v : expm1f(v);
}

extern "C" void kernel_launch(void* const* d_in, const int* in_sizes, int n_in,
                              void* d_out, int out_size, void* d_ws, size_t ws_size,
                              hipStream_t stream) {
    const float* x    = (const float*)d_in[0];
    const float* rel  = (const float*)d_in[1];
    const float* adj  = (const float*)d_in[2];
    const int*   ep   = (const int*)d_in[3];
    const int*   rseg = (const int*)d_in[4];
    const float* W    = (const float*)d_in[5];
    const float* wrel = (const float*)d_in[6];
    const float* bias = (const float*)d_in[7];
    float* out = (float*)d_out;

    float* ws = (float*)d_ws;
    float*    sums  = ws + O_SUMS;
    float*    cnts  = ws + O_CNTS;
    float*    S     = ws + O_S;
    float*    Num   = ws + O_NUM;
    unsigned* hkey  = (unsigned*)(ws + O_HKEY);
    unsigned* hprio = (unsigned*)(ws + O_HPRIO);
    float*    means = ws + O_MEANS;
    float*    seq   = ws + O_SEQ;
    float*    dwbuf = ws + O_DW;

    hipMemsetAsync(d_ws, 0, (size_t)ZERO_WORDS * 4, stream);

    k_seqfts<<<NN / 16, 256, 0, stream>>>(x, W, seq);
    k_rel<<<(RR * 32) / 256, 256, 0, stream>>>(rel, wrel, rseg, sums, cnts);
    k_means<<<(EE + 255) / 256, 256, 0, stream>>>(sums, cnts, means);
    k_scatA<<<(2 * EE + 255) / 256, 256, 0, stream>>>(ep, hkey, hprio);
    k_main<<<dim3(NCHUNK, KSPLIT), 256, 0, stream>>>(adj, seq, Num, S);
    k_scatB<<<(2 * EE + 255) / 256, 256, 0, stream>>>(ep, means, hkey, hprio, adj, S, dwbuf);
    k_scatC<<<(2 * EE * 64) / 256, 256, 0, stream>>>(ep, dwbuf, seq, Num);
    k_final<<<(NN * FOUT + 255) / 256, 256, 0, stream>>>(Num, S, bias, out);
}

// Round 2
// 356.860 us; speedup vs baseline: 1.5361x; 1.5361x over previous
//
#include <hip/hip_runtime.h>
#include <math.h>

#define NN   10000
#define EE   200000
#define RR   400000
#define FIN  128
#define FOUT 64
#define NK   10048           // 157*64, K padded for seqT

#define HASH_BITS 20
#define HSIZE (1u << HASH_BITS)
#define HMASK (HSIZE - 1u)

typedef __bf16 bf16x8 __attribute__((ext_vector_type(8)));
typedef __bf16 bf16x4 __attribute__((ext_vector_type(4)));
typedef float  f32x4  __attribute__((ext_vector_type(4)));

// ---- workspace layout (units of 4 bytes) ----
#define O_SUMS  0
#define O_CNTS  (O_SUMS + EE)
#define O_S     (O_CNTS + EE)
#define O_NUM   (O_S + NN)
#define O_HKEY  (O_NUM + NN * FOUT)
#define O_HPRIO (O_HKEY + HSIZE)
#define O_SEQT  (O_HPRIO + HSIZE)          // bf16[64][NK] = 64*NK/2 words
#define ZERO_WORDS (O_SEQT + (FOUT * NK) / 2)
#define O_SEQ   ZERO_WORDS
#define O_DW    (O_SEQ + NN * FOUT)

// ---------------- seq_fts = x @ W^T  (also emits bf16 transposed copy) ----
__global__ __launch_bounds__(256) void k_seqfts(const float* __restrict__ x,
                                                const float* __restrict__ W,
                                                float* __restrict__ seq,
                                                __bf16* __restrict__ seqT) {
    __shared__ float Wt[FIN][FOUT + 1];
    __shared__ float xs[FIN][16 + 1];
    int t = threadIdx.x;
    for (int e = t; e < FOUT * FIN; e += 256) {
        int c = e >> 7, k = e & 127;
        Wt[k][c] = W[e];
    }
    int row0 = blockIdx.x * 16;
    for (int e = t; e < 16 * FIN; e += 256) {
        int r = e >> 7, k = e & 127;
        int gr = row0 + r;
        xs[k][r] = (gr < NN) ? x[(size_t)gr * FIN + k] : 0.f;
    }
    __syncthreads();
    int col = t & 63;
    int rg  = t >> 6;
    float acc[4] = {0.f, 0.f, 0.f, 0.f};
    for (int k = 0; k < FIN; ++k) {
        float w = Wt[k][col];
        #pragma unroll
        for (int i = 0; i < 4; ++i) acc[i] += w * xs[k][rg * 4 + i];
    }
    #pragma unroll
    for (int i = 0; i < 4; ++i) {
        int gr = row0 + rg * 4 + i;
        if (gr < NN) {
            seq[(size_t)gr * FOUT + col] = acc[i];
            seqT[(size_t)col * NK + gr] = (__bf16)acc[i];
        }
    }
}

// ---------------- fts_rel dot + segment sums ----------------
__global__ __launch_bounds__(256) void k_rel(const float* __restrict__ rel,
                                             const float* __restrict__ wrel,
                                             const int* __restrict__ rseg,
                                             float* __restrict__ sums,
                                             float* __restrict__ cnts) {
    int gid  = blockIdx.x * 256 + threadIdx.x;
    int row  = gid >> 5;
    int lane = gid & 31;
    if (row >= RR) return;
    float4 v = *(const float4*)(rel + (size_t)row * FIN + lane * 4);
    float4 w = *(const float4*)(wrel + lane * 4);
    float s = v.x * w.x + v.y * w.y + v.z * w.z + v.w * w.w;
    #pragma unroll
    for (int off = 16; off >= 1; off >>= 1) s += __shfl_xor(s, off, 64);
    if (lane == 0) {
        int seg = rseg[row];
        atomicAdd(&sums[seg], s);
        atomicAdd(&cnts[seg], 1.0f);
    }
}

// ---------------- scatter duplicate resolution ----------------
__device__ __forceinline__ unsigned hash_cell(unsigned cell) {
    return (cell * 2654435761u) >> (32 - HASH_BITS);
}

__device__ __forceinline__ void entry_ij(const int* ep, int e, int& i, int& j, int& k) {
    k = (e < EE) ? e : e - EE;
    int a = ep[2 * k], b = ep[2 * k + 1];
    if (e < EE) { i = a; j = b; } else { i = b; j = a; }
}

__global__ void k_scatA(const int* __restrict__ ep,
                        unsigned* __restrict__ hkey,
                        unsigned* __restrict__ hprio) {
    int e = blockIdx.x * 256 + threadIdx.x;
    if (e >= 2 * EE) return;
    int i, j, k;
    entry_ij(ep, e, i, j, k);
    unsigned cell = (unsigned)i * NN + (unsigned)j;
    unsigned keyv = cell + 1u;
    unsigned h = hash_cell(cell);
    while (true) {
        unsigned old = atomicCAS(&hkey[h], 0u, keyv);
        if (old == 0u || old == keyv) break;
        h = (h + 1u) & HMASK;
    }
    atomicMax(&hprio[h], (unsigned)(e + 1));
}

__global__ void k_scatB(const int* __restrict__ ep,
                        const float* __restrict__ sums,
                        const float* __restrict__ cnts,
                        const unsigned* __restrict__ hkey,
                        const unsigned* __restrict__ hprio,
                        const float* __restrict__ adj,
                        float* __restrict__ S,
                        float* __restrict__ dwbuf) {
    int e = blockIdx.x * 256 + threadIdx.x;
    if (e >= 2 * EE) return;
    int i, j, k;
    entry_ij(ep, e, i, j, k);
    unsigned cell = (unsigned)i * NN + (unsigned)j;
    unsigned keyv = cell + 1u;
    unsigned h = hash_cell(cell);
    while (hkey[h] != keyv) h = (h + 1u) & HMASK;
    float dw = 0.f;
    if (hprio[h] == (unsigned)(e + 1)) {   // last-write-wins winner
        float v  = sums[k] / fmaxf(cnts[k], 1.0f);
        float sg = 1.f / (1.f + __expf(-v));
        float aij = adj[(size_t)i * NN + j];
        dw = __expf(aij + sg) - __expf(aij + 0.5f);
        if (dw != 0.f) atomicAdd(&S[i], dw);
    }
    dwbuf[e] = dw;
}

// one 64-lane wave per entry: Num[i,:] += dw * seq[j,:]
__global__ __launch_bounds__(256) void k_scatC(const int* __restrict__ ep,
                                               const float* __restrict__ dwbuf,
                                               const float* __restrict__ seq,
                                               float* __restrict__ Num) {
    int gid  = blockIdx.x * 256 + threadIdx.x;
    int e    = gid >> 6;
    int lane = gid & 63;
    if (e >= 2 * EE) return;
    float dw = dwbuf[e];
    if (dw == 0.f) return;
    int i, j, k;
    entry_ij(ep, e, i, j, k);
    atomicAdd(&Num[(size_t)i * FOUT + lane], dw * seq[(size_t)j * FOUT + lane]);
}

// ---------------- main: Num = exp(adj+0.5) @ seq (bf16 MFMA), S = rowsum ----
#define BM 64
#define BK 64
#define KSPLIT 8
#define NCHUNK 157
#define LDAP (BK + 8)   // bf16 leading dim pad: +16B keeps b128 alignment

__global__ __launch_bounds__(256) void k_main(const float* __restrict__ adj,
                                              const __bf16* __restrict__ seqT,
                                              float* __restrict__ Num,
                                              float* __restrict__ S) {
    __shared__ __bf16 As[BM][LDAP];
    __shared__ __bf16 Bs[FOUT][LDAP];
    int t    = threadIdx.x;
    int row0 = blockIdx.x * BM;
    int cpk  = (NCHUNK + KSPLIT - 1) / KSPLIT;  // 20
    int c0   = blockIdx.y * cpk;
    int c1   = min(NCHUNK, c0 + cpk);
    int w = t >> 6, l = t & 63;
    int lr = l & 15, lk = l >> 4;

    f32x4 acc[4];
    #pragma unroll
    for (int n = 0; n < 4; ++n) acc[n] = (f32x4){0.f, 0.f, 0.f, 0.f};
    float rs[4] = {0.f, 0.f, 0.f, 0.f};

    for (int ch = c0; ch < c1; ++ch) {
        int k0 = ch * BK;
        // stage B = seqT[col][k0..k0+63]  (pad rows of seqT are zero)
        #pragma unroll
        for (int e = 0; e < 2; ++e) {
            int idx = e * 256 + t;
            int c = idx >> 3, kk = (idx & 7) * 8;
            *(bf16x8*)&Bs[c][kk] = *(const bf16x8*)(seqT + (size_t)c * NK + k0 + kk);
        }
        // stage A = bf16(exp(adj+0.5)), accumulate f32 row-sums in regs
        #pragma unroll
        for (int e = 0; e < 4; ++e) {
            int idx = e * 256 + t;
            int r = idx >> 4, kk = (idx & 15) * 4;
            int gr = row0 + r, gk = k0 + kk;
            bool ok = (gr < NN) && (gk < NN);
            float4 vv = make_float4(0.f, 0.f, 0.f, 0.f);
            if (ok) vv = *(const float4*)(adj + (size_t)gr * NN + gk);
            float w0 = ok ? __expf(vv.x + 0.5f) : 0.f;
            float w1 = ok ? __expf(vv.y + 0.5f) : 0.f;
            float w2 = ok ? __expf(vv.z + 0.5f) : 0.f;
            float w3 = ok ? __expf(vv.w + 0.5f) : 0.f;
            bf16x4 bv = { (__bf16)w0, (__bf16)w1, (__bf16)w2, (__bf16)w3 };
            *(bf16x4*)&As[r][kk] = bv;
            rs[e] += w0 + w1 + w2 + w3;
        }
        __syncthreads();
        // 16 rows x 64 cols per wave: 2 K-substeps x 4 col-fragments
        #pragma unroll
        for (int ks = 0; ks < 2; ++ks) {
            bf16x8 a = *(const bf16x8*)&As[w * 16 + lr][ks * 32 + lk * 8];
            #pragma unroll
            for (int n = 0; n < 4; ++n) {
                bf16x8 b = *(const bf16x8*)&Bs[n * 16 + lr][ks * 32 + lk * 8];
                acc[n] = __builtin_amdgcn_mfma_f32_16x16x32_bf16(a, b, acc[n], 0, 0, 0);
            }
        }
        __syncthreads();
    }
    // row-sum: reduce across the 16 lanes sharing a row, one atomic per row
    #pragma unroll
    for (int e = 0; e < 4; ++e) {
        float p = rs[e];
        p += __shfl_xor(p, 1, 64);
        p += __shfl_xor(p, 2, 64);
        p += __shfl_xor(p, 4, 64);
        p += __shfl_xor(p, 8, 64);
        int r = e * 16 + (t >> 4);
        if ((t & 15) == 0 && row0 + r < NN) atomicAdd(&S[row0 + r], p);
    }
    // C/D layout: col = lane&15, row = (lane>>4)*4 + reg
    #pragma unroll
    for (int n = 0; n < 4; ++n) {
        #pragma unroll
        for (int r = 0; r < 4; ++r) {
            int grow = row0 + w * 16 + lk * 4 + r;
            if (grow < NN)
                atomicAdd(&Num[(size_t)grow * FOUT + n * 16 + lr], acc[n][r]);
        }
    }
}

// ---------------- finalize: elu(Num/S + bias) ----------------
__global__ void k_final(const float* __restrict__ Num,
                        const float* __restrict__ S,
                        const float* __restrict__ bias,
                        float* __restrict__ out) {
    int gid = blockIdx.x * 256 + threadIdx.x;
    if (gid >= NN * FOUT) return;
    int i = gid >> 6, c = gid & 63;
    float v = Num[gid] / S[i] + bias[c];
    out[gid] = (v > 0.f) ? v : expm1f(v);
}

extern "C" void kernel_launch(void* const* d_in, const int* in_sizes, int n_in,
                              void* d_out, int out_size, void* d_ws, size_t ws_size,
                              hipStream_t stream) {
    const float* x    = (const float*)d_in[0];
    const float* rel  = (const float*)d_in[1];
    const float* adj  = (const float*)d_in[2];
    const int*   ep   = (const int*)d_in[3];
    const int*   rseg = (const int*)d_in[4];
    const float* W    = (const float*)d_in[5];
    const float* wrel = (const float*)d_in[6];
    const float* bias = (const float*)d_in[7];
    float* out = (float*)d_out;

    float* ws = (float*)d_ws;
    float*    sums  = ws + O_SUMS;
    float*    cnts  = ws + O_CNTS;
    float*    S     = ws + O_S;
    float*    Num   = ws + O_NUM;
    unsigned* hkey  = (unsigned*)(ws + O_HKEY);
    unsigned* hprio = (unsigned*)(ws + O_HPRIO);
    __bf16*   seqT  = (__bf16*)(ws + O_SEQT);
    float*    seq   = ws + O_SEQ;
    float*    dwbuf = ws + O_DW;

    hipMemsetAsync(d_ws, 0, (size_t)ZERO_WORDS * 4, stream);

    k_seqfts<<<NN / 16, 256, 0, stream>>>(x, W, seq, seqT);
    k_rel<<<(RR * 32) / 256, 256, 0, stream>>>(rel, wrel, rseg, sums, cnts);
    k_scatA<<<(2 * EE + 255) / 256, 256, 0, stream>>>(ep, hkey, hprio);
    k_main<<<dim3(NCHUNK, KSPLIT), 256, 0, stream>>>(adj, seqT, Num, S);
    k_scatB<<<(2 * EE + 255) / 256, 256, 0, stream>>>(ep, sums, cnts, hkey, hprio, adj, S, dwbuf);
    k_scatC<<<(2 * EE * 64) / 256, 256, 0, stream>>>(ep, dwbuf, seq, Num);
    k_final<<<(NN * FOUT + 255) / 256, 256, 0, stream>>>(Num, S, bias, out);
}

// Round 4
// 335.413 us; speedup vs baseline: 1.6343x; 1.0639x over previous
//
#include <hip/hip_runtime.h>
#include <math.h>

#define NN   10000
#define EE   200000
#define RR   400000
#define FIN  128
#define FOUT 64
#define NK   10048           // 157*64, K padded for seqT

#define HASH_BITS 20
#define HSIZE (1u << HASH_BITS)
#define HMASK (HSIZE - 1u)

typedef __bf16 bf16x8 __attribute__((ext_vector_type(8)));
typedef __bf16 bf16x4 __attribute__((ext_vector_type(4)));
typedef float  f32x4  __attribute__((ext_vector_type(4)));

// ---- workspace layout (units of 4 bytes) ----
#define O_SUMS  0
#define O_CNTS  (O_SUMS + EE)
#define O_S     (O_CNTS + EE)
#define O_NUM   (O_S + NN)
#define O_HKEY  (O_NUM + NN * FOUT)
#define O_HPRIO (O_HKEY + HSIZE)
#define O_SEQT  (O_HPRIO + HSIZE)          // bf16[64][NK]
#define ZERO_WORDS (O_SEQT + (FOUT * NK) / 2)
#define O_SEQ   ZERO_WORDS

// ---------------- seq_fts = x @ W^T  (also emits bf16 transposed copy) ----
__global__ __launch_bounds__(256) void k_seqfts(const float* __restrict__ x,
                                                const float* __restrict__ W,
                                                float* __restrict__ seq,
                                                __bf16* __restrict__ seqT) {
    __shared__ float Wt[FIN][FOUT + 1];
    __shared__ float xs[FIN][16 + 1];
    int t = threadIdx.x;
    for (int e = t; e < FOUT * FIN; e += 256) {
        int c = e >> 7, k = e & 127;
        Wt[k][c] = W[e];
    }
    int row0 = blockIdx.x * 16;
    for (int e = t; e < 16 * FIN; e += 256) {
        int r = e >> 7, k = e & 127;
        int gr = row0 + r;
        xs[k][r] = (gr < NN) ? x[(size_t)gr * FIN + k] : 0.f;
    }
    __syncthreads();
    int col = t & 63;
    int rg  = t >> 6;
    float acc[4] = {0.f, 0.f, 0.f, 0.f};
    for (int k = 0; k < FIN; ++k) {
        float w = Wt[k][col];
        #pragma unroll
        for (int i = 0; i < 4; ++i) acc[i] += w * xs[k][rg * 4 + i];
    }
    #pragma unroll
    for (int i = 0; i < 4; ++i) {
        int gr = row0 + rg * 4 + i;
        if (gr < NN) {
            seq[(size_t)gr * FOUT + col] = acc[i];
            seqT[(size_t)col * NK + gr] = (__bf16)acc[i];
        }
    }
}

// ---------------- scatter duplicate resolution ----------------
__device__ __forceinline__ unsigned hash_cell(unsigned cell) {
    return (cell * 2654435761u) >> (32 - HASH_BITS);
}

__device__ __forceinline__ void entry_ij(const int* ep, int e, int& i, int& j, int& k) {
    k = (e < EE) ? e : e - EE;
    int a = ep[2 * k], b = ep[2 * k + 1];
    if (e < EE) { i = a; j = b; } else { i = b; j = a; }
}

__global__ void k_scatA(const int* __restrict__ ep,
                        unsigned* __restrict__ hkey,
                        unsigned* __restrict__ hprio) {
    int e = blockIdx.x * 256 + threadIdx.x;
    if (e >= 2 * EE) return;
    int i, j, k;
    entry_ij(ep, e, i, j, k);
    unsigned cell = (unsigned)i * NN + (unsigned)j;
    unsigned keyv = cell + 1u;
    unsigned h = hash_cell(cell);
    while (true) {
        unsigned old = atomicCAS(&hkey[h], 0u, keyv);
        if (old == 0u || old == keyv) break;
        h = (h + 1u) & HMASK;
    }
    atomicMax(&hprio[h], (unsigned)(e + 1));
}

// ---------------- merged: Num = exp(adj+0.5) @ seq (MFMA)  ||  rel segsum ---
#define BM 64
#define BK 64
#define KSPLIT 8
#define NCHUNK 157
#define CPK ((NCHUNK + KSPLIT - 1) / KSPLIT)   // 20
#define MAINB (NCHUNK * KSPLIT)                // 1256
#define RELB  (RR / 8)                         // 50000
#define LDAP (BK + 8)

__global__ __launch_bounds__(256) void k_mainrel(const float* __restrict__ adj,
                                                 const __bf16* __restrict__ seqT,
                                                 const float* __restrict__ rel,
                                                 const float* __restrict__ wrel,
                                                 const int* __restrict__ rseg,
                                                 float* __restrict__ sums,
                                                 float* __restrict__ cnts,
                                                 float* __restrict__ Num,
                                                 float* __restrict__ S) {
    __shared__ __bf16 As[BM][LDAP];
    __shared__ __bf16 Bs[FOUT][LDAP];
    int t   = threadIdx.x;
    int bid = blockIdx.x;

    if (bid >= MAINB) {
        // ---- rel role: one 32-lane group per relation row ----
        int gid  = (bid - MAINB) * 256 + t;
        int row  = gid >> 5;
        int lane = gid & 31;
        f32x4 v = __builtin_nontemporal_load(
            (const f32x4*)(rel + (size_t)row * FIN + lane * 4));
        f32x4 w = *(const f32x4*)(wrel + lane * 4);
        float s = v.x * w.x + v.y * w.y + v.z * w.z + v.w * w.w;
        #pragma unroll
        for (int off = 16; off >= 1; off >>= 1) s += __shfl_xor(s, off, 64);
        if (lane == 0) {
            int seg = rseg[row];
            atomicAdd(&sums[seg], s);
            atomicAdd(&cnts[seg], 1.0f);
        }
        return;
    }

    // ---- main role ----
    int rowc = bid % NCHUNK;
    int ks   = bid / NCHUNK;
    int row0 = rowc * BM;
    int c0   = ks * CPK;
    int c1   = min(NCHUNK, c0 + CPK);
    int w  = t >> 6, l = t & 63;
    int lr = l & 15, lk = l >> 4;
    int sr = t >> 4;               // A-stage row within 16-row strip
    int sk = (t & 15) * 4;         // A-stage col (float4)
    int bc = t >> 3;               // B-stage col 0..31 (+32)
    int bk = (t & 7) * 8;          // B-stage k (bf16x8)

    f32x4 acc[4];
    #pragma unroll
    for (int n = 0; n < 4; ++n) acc[n] = (f32x4){0.f, 0.f, 0.f, 0.f};
    float rs[4] = {0.f, 0.f, 0.f, 0.f};

    f32x4  pva[4];
    bf16x8 pvb0, pvb1;

#define LOADC(CH)                                                              \
    {                                                                          \
        int k0_ = (CH) * BK;                                                   \
        _Pragma("unroll")                                                      \
        for (int e2 = 0; e2 < 4; ++e2) {                                       \
            int gr = row0 + sr + e2 * 16;                                      \
            int gk = k0_ + sk;                                                 \
            bool ok = (gr < NN) && (gk < NN);                                  \
            pva[e2] = ok ? __builtin_nontemporal_load(                         \
                               (const f32x4*)(adj + (size_t)gr * NN + gk))     \
                         : (f32x4){0.f, 0.f, 0.f, 0.f};                        \
        }                                                                      \
        pvb0 = *(const bf16x8*)(seqT + (size_t)bc * NK + k0_ + bk);            \
        pvb1 = *(const bf16x8*)(seqT + (size_t)(bc + 32) * NK + k0_ + bk);     \
    }

    LOADC(c0);
    for (int ch = c0; ch < c1; ++ch) {
        f32x4  va[4] = { pva[0], pva[1], pva[2], pva[3] };
        bf16x8 vb0 = pvb0, vb1 = pvb1;
        if (ch + 1 < c1) LOADC(ch + 1);                     // fly during compute

        *(bf16x8*)&Bs[bc][bk]      = vb0;
        *(bf16x8*)&Bs[bc + 32][bk] = vb1;

        int  k0c = ch * BK;
        bool okk = (k0c + sk < NN);
        #pragma unroll
        for (int e2 = 0; e2 < 4; ++e2) {
            bool ok = okk && (row0 + sr + e2 * 16 < NN);
            float w0 = ok ? __expf(va[e2].x + 0.5f) : 0.f;
            float w1 = ok ? __expf(va[e2].y + 0.5f) : 0.f;
            float w2 = ok ? __expf(va[e2].z + 0.5f) : 0.f;
            float w3 = ok ? __expf(va[e2].w + 0.5f) : 0.f;
            bf16x4 bv = { (__bf16)w0, (__bf16)w1, (__bf16)w2, (__bf16)w3 };
            *(bf16x4*)&As[sr + e2 * 16][sk] = bv;
            rs[e2] += w0 + w1 + w2 + w3;
        }
        __syncthreads();
        #pragma unroll
        for (int kss = 0; kss < 2; ++kss) {
            bf16x8 a = *(const bf16x8*)&As[w * 16 + lr][kss * 32 + lk * 8];
            #pragma unroll
            for (int n = 0; n < 4; ++n) {
                bf16x8 b = *(const bf16x8*)&Bs[n * 16 + lr][kss * 32 + lk * 8];
                acc[n] = __builtin_amdgcn_mfma_f32_16x16x32_bf16(a, b, acc[n], 0, 0, 0);
            }
        }
        __syncthreads();
    }
#undef LOADC

    // row-sum: reduce across 16 lanes sharing a row, one atomic per row
    #pragma unroll
    for (int e = 0; e < 4; ++e) {
        float p = rs[e];
        p += __shfl_xor(p, 1, 64);
        p += __shfl_xor(p, 2, 64);
        p += __shfl_xor(p, 4, 64);
        p += __shfl_xor(p, 8, 64);
        int r = e * 16 + sr;
        if ((t & 15) == 0 && row0 + r < NN) atomicAdd(&S[row0 + r], p);
    }
    // C/D layout: col = lane&15, row = (lane>>4)*4 + reg
    #pragma unroll
    for (int n = 0; n < 4; ++n) {
        #pragma unroll
        for (int r = 0; r < 4; ++r) {
            int grow = row0 + w * 16 + lk * 4 + r;
            if (grow < NN)
                atomicAdd(&Num[(size_t)grow * FOUT + n * 16 + lr], acc[n][r]);
        }
    }
}

// ---------------- merged scatter: dw compute + Num/S update ----------------
__global__ __launch_bounds__(256) void k_scat2(const int* __restrict__ ep,
                                               const float* __restrict__ sums,
                                               const float* __restrict__ cnts,
                                               const unsigned* __restrict__ hkey,
                                               const unsigned* __restrict__ hprio,
                                               const float* __restrict__ adj,
                                               const float* __restrict__ seq,
                                               float* __restrict__ S,
                                               float* __restrict__ Num) {
    __shared__ float dws[256];
    __shared__ int   iis[256];
    __shared__ int   jjs[256];
    int t = threadIdx.x;
    int e = blockIdx.x * 256 + t;
    float dw = 0.f;
    int i = 0, j = 0;
    if (e < 2 * EE) {
        int k;
        entry_ij(ep, e, i, j, k);
        unsigned cell = (unsigned)i * NN + (unsigned)j;
        unsigned keyv = cell + 1u;
        unsigned h = hash_cell(cell);
        while (hkey[h] != keyv) h = (h + 1u) & HMASK;
        if (hprio[h] == (unsigned)(e + 1)) {   // last-write-wins winner
            float v   = sums[k] / fmaxf(cnts[k], 1.0f);
            float sg  = 1.f / (1.f + __expf(-v));
            float aij = adj[(size_t)i * NN + j];
            dw = __expf(aij + sg) - __expf(aij + 0.5f);
            if (dw != 0.f) atomicAdd(&S[i], dw);
        }
    }
    dws[t] = dw; iis[t] = i; jjs[t] = j;
    __syncthreads();
    int w = t >> 6, lane = t & 63;
    for (int q = 0; q < 64; ++q) {
        int idx = w * 64 + q;
        float d = dws[idx];                    // broadcast read
        if (d != 0.f) {
            atomicAdd(&Num[(size_t)iis[idx] * FOUT + lane],
                      d * seq[(size_t)jjs[idx] * FOUT + lane]);
        }
    }
}

// ---------------- finalize: elu(Num/S + bias) ----------------
__global__ void k_final(const float* __restrict__ Num,
                        const float* __restrict__ S,
                        const float* __restrict__ bias,
                        float* __restrict__ out) {
    int gid = blockIdx.x * 256 + threadIdx.x;
    if (gid >= NN * FOUT) return;
    int i = gid >> 6, c = gid & 63;
    float v = Num[gid] / S[i] + bias[c];
    out[gid] = (v > 0.f) ? v : expm1f(v);
}

extern "C" void kernel_launch(void* const* d_in, const int* in_sizes, int n_in,
                              void* d_out, int out_size, void* d_ws, size_t ws_size,
                              hipStream_t stream) {
    const float* x    = (const float*)d_in[0];
    const float* rel  = (const float*)d_in[1];
    const float* adj  = (const float*)d_in[2];
    const int*   ep   = (const int*)d_in[3];
    const int*   rseg = (const int*)d_in[4];
    const float* W    = (const float*)d_in[5];
    const float* wrel = (const float*)d_in[6];
    const float* bias = (const float*)d_in[7];
    float* out = (float*)d_out;

    float* ws = (float*)d_ws;
    float*    sums  = ws + O_SUMS;
    float*    cnts  = ws + O_CNTS;
    float*    S     = ws + O_S;
    float*    Num   = ws + O_NUM;
    unsigned* hkey  = (unsigned*)(ws + O_HKEY);
    unsigned* hprio = (unsigned*)(ws + O_HPRIO);
    __bf16*   seqT  = (__bf16*)(ws + O_SEQT);
    float*    seq   = ws + O_SEQ;

    (void)hipMemsetAsync(d_ws, 0, (size_t)ZERO_WORDS * 4, stream);

    k_seqfts<<<NN / 16, 256, 0, stream>>>(x, W, seq, seqT);
    k_scatA<<<(2 * EE + 255) / 256, 256, 0, stream>>>(ep, hkey, hprio);
    k_mainrel<<<MAINB + RELB, 256, 0, stream>>>(adj, seqT, rel, wrel, rseg,
                                                sums, cnts, Num, S);
    k_scat2<<<(2 * EE + 255) / 256, 256, 0, stream>>>(ep, sums, cnts, hkey, hprio,
                                                      adj, seq, S, Num);
    k_final<<<(NN * FOUT + 255) / 256, 256, 0, stream>>>(Num, S, bias, out);
}

// Round 5
// 333.869 us; speedup vs baseline: 1.6418x; 1.0046x over previous
//
#include <hip/hip_runtime.h>
#include <math.h>

#define NN   10000
#define EE   200000
#define RR   400000
#define FIN  128
#define FOUT 64
#define NK   10048           // 157*64, K padded for seqT

#define HASH_BITS 20
#define HSIZE (1u << HASH_BITS)
#define HMASK (HSIZE - 1u)

typedef __bf16 bf16x8 __attribute__((ext_vector_type(8)));
typedef __bf16 bf16x4 __attribute__((ext_vector_type(4)));
typedef float  f32x4  __attribute__((ext_vector_type(4)));

// ---- workspace layout (units of 4 bytes) ----
#define O_SUMS  0
#define O_CNTS  (O_SUMS + EE)
#define O_S     (O_CNTS + EE)
#define O_NUM   (O_S + NN)
#define O_HKEY  (O_NUM + NN * FOUT)
#define O_HPRIO (O_HKEY + HSIZE)
#define O_SEQT  (O_HPRIO + HSIZE)          // bf16[64][NK]
#define ZERO_WORDS (O_SEQT + (FOUT * NK) / 2)
#define O_SEQ   ZERO_WORDS

// ---------------- wide zero fill (replaces runtime fillBuffer @55GB/s) ----
__global__ __launch_bounds__(256) void k_zero(f32x4* __restrict__ p, int n4) {
    int gid = blockIdx.x * 256 + threadIdx.x;
    if (gid < n4) p[gid] = (f32x4){0.f, 0.f, 0.f, 0.f};
}

// ---------------- seq_fts = x @ W^T  (also emits bf16 transposed copy) ----
__global__ __launch_bounds__(256) void k_seqfts(const float* __restrict__ x,
                                                const float* __restrict__ W,
                                                float* __restrict__ seq,
                                                __bf16* __restrict__ seqT) {
    __shared__ float Wt[FIN][FOUT + 1];
    __shared__ float xs[FIN][16 + 1];
    int t = threadIdx.x;
    for (int e = t; e < FOUT * FIN; e += 256) {
        int c = e >> 7, k = e & 127;
        Wt[k][c] = W[e];
    }
    int row0 = blockIdx.x * 16;
    for (int e = t; e < 16 * FIN; e += 256) {
        int r = e >> 7, k = e & 127;
        int gr = row0 + r;
        xs[k][r] = (gr < NN) ? x[(size_t)gr * FIN + k] : 0.f;
    }
    __syncthreads();
    int col = t & 63;
    int rg  = t >> 6;
    float acc[4] = {0.f, 0.f, 0.f, 0.f};
    for (int k = 0; k < FIN; ++k) {
        float w = Wt[k][col];
        #pragma unroll
        for (int i = 0; i < 4; ++i) acc[i] += w * xs[k][rg * 4 + i];
    }
    #pragma unroll
    for (int i = 0; i < 4; ++i) {
        int gr = row0 + rg * 4 + i;
        if (gr < NN) {
            seq[(size_t)gr * FOUT + col] = acc[i];
            seqT[(size_t)col * NK + gr] = (__bf16)acc[i];
        }
    }
}

// ---------------- scatter duplicate resolution ----------------
__device__ __forceinline__ unsigned hash_cell(unsigned cell) {
    return (cell * 2654435761u) >> (32 - HASH_BITS);
}

__device__ __forceinline__ void entry_ij(const int* ep, int e, int& i, int& j, int& k) {
    k = (e < EE) ? e : e - EE;
    int a = ep[2 * k], b = ep[2 * k + 1];
    if (e < EE) { i = a; j = b; } else { i = b; j = a; }
}

__global__ void k_scatA(const int* __restrict__ ep,
                        unsigned* __restrict__ hkey,
                        unsigned* __restrict__ hprio) {
    int e = blockIdx.x * 256 + threadIdx.x;
    if (e >= 2 * EE) return;
    int i, j, k;
    entry_ij(ep, e, i, j, k);
    unsigned cell = (unsigned)i * NN + (unsigned)j;
    unsigned keyv = cell + 1u;
    unsigned h = hash_cell(cell);
    while (true) {
        unsigned old = atomicCAS(&hkey[h], 0u, keyv);
        if (old == 0u || old == keyv) break;
        h = (h + 1u) & HMASK;
    }
    atomicMax(&hprio[h], (unsigned)(e + 1));
}

// ---------------- merged: Num = exp(adj+0.5) @ seq (MFMA)  ||  rel segsum ---
#define BM 64
#define BK 64
#define KSPLIT 8
#define NCHUNK 157
#define CPK ((NCHUNK + KSPLIT - 1) / KSPLIT)   // 20
#define MAINB (NCHUNK * KSPLIT)                // 1256
#define RELB  (RR / 8)                         // 50000
#define LDAP (BK + 8)

__global__ __launch_bounds__(256) void k_mainrel(const float* __restrict__ adj,
                                                 const __bf16* __restrict__ seqT,
                                                 const float* __restrict__ rel,
                                                 const float* __restrict__ wrel,
                                                 const int* __restrict__ rseg,
                                                 float* __restrict__ sums,
                                                 float* __restrict__ cnts,
                                                 float* __restrict__ Num,
                                                 float* __restrict__ S) {
    __shared__ __bf16 As[BM][LDAP];
    __shared__ __bf16 Bs[FOUT][LDAP];
    int t   = threadIdx.x;
    int bid = blockIdx.x;

    if (bid >= MAINB) {
        // ---- rel role: one 32-lane group per relation row ----
        int gid  = (bid - MAINB) * 256 + t;
        int row  = gid >> 5;
        int lane = gid & 31;
        f32x4 v = __builtin_nontemporal_load(
            (const f32x4*)(rel + (size_t)row * FIN + lane * 4));
        f32x4 w = *(const f32x4*)(wrel + lane * 4);
        float s = v.x * w.x + v.y * w.y + v.z * w.z + v.w * w.w;
        #pragma unroll
        for (int off = 16; off >= 1; off >>= 1) s += __shfl_xor(s, off, 64);
        if (lane == 0) {
            int seg = rseg[row];
            atomicAdd(&sums[seg], s);
            atomicAdd(&cnts[seg], 1.0f);
        }
        return;
    }

    // ---- main role ----
    int rowc = bid % NCHUNK;
    int ks   = bid / NCHUNK;
    int row0 = rowc * BM;
    int c0   = ks * CPK;
    int c1   = min(NCHUNK, c0 + CPK);
    int w  = t >> 6, l = t & 63;
    int lr = l & 15, lk = l >> 4;
    int sr = t >> 4;               // A-stage row within 16-row strip
    int sk = (t & 15) * 4;         // A-stage col (float4)
    int bc = t >> 3;               // B-stage col 0..31 (+32)
    int bk = (t & 7) * 8;          // B-stage k (bf16x8)

    f32x4 acc[4];
    #pragma unroll
    for (int n = 0; n < 4; ++n) acc[n] = (f32x4){0.f, 0.f, 0.f, 0.f};
    float rs[4] = {0.f, 0.f, 0.f, 0.f};

    f32x4  pva[4];
    bf16x8 pvb0, pvb1;

#define LOADC(CH)                                                              \
    {                                                                          \
        int k0_ = (CH) * BK;                                                   \
        _Pragma("unroll")                                                      \
        for (int e2 = 0; e2 < 4; ++e2) {                                       \
            int gr = row0 + sr + e2 * 16;                                      \
            int gk = k0_ + sk;                                                 \
            bool ok = (gr < NN) && (gk < NN);                                  \
            pva[e2] = ok ? __builtin_nontemporal_load(                         \
                               (const f32x4*)(adj + (size_t)gr * NN + gk))     \
                         : (f32x4){0.f, 0.f, 0.f, 0.f};                        \
        }                                                                      \
        pvb0 = *(const bf16x8*)(seqT + (size_t)bc * NK + k0_ + bk);            \
        pvb1 = *(const bf16x8*)(seqT + (size_t)(bc + 32) * NK + k0_ + bk);     \
    }

    LOADC(c0);
    for (int ch = c0; ch < c1; ++ch) {
        f32x4  va[4] = { pva[0], pva[1], pva[2], pva[3] };
        bf16x8 vb0 = pvb0, vb1 = pvb1;
        if (ch + 1 < c1) LOADC(ch + 1);                     // fly during compute

        *(bf16x8*)&Bs[bc][bk]      = vb0;
        *(bf16x8*)&Bs[bc + 32][bk] = vb1;

        int  k0c = ch * BK;
        bool okk = (k0c + sk < NN);
        #pragma unroll
        for (int e2 = 0; e2 < 4; ++e2) {
            bool ok = okk && (row0 + sr + e2 * 16 < NN);
            float w0 = ok ? __expf(va[e2].x + 0.5f) : 0.f;
            float w1 = ok ? __expf(va[e2].y + 0.5f) : 0.f;
            float w2 = ok ? __expf(va[e2].z + 0.5f) : 0.f;
            float w3 = ok ? __expf(va[e2].w + 0.5f) : 0.f;
            bf16x4 bv = { (__bf16)w0, (__bf16)w1, (__bf16)w2, (__bf16)w3 };
            *(bf16x4*)&As[sr + e2 * 16][sk] = bv;
            rs[e2] += w0 + w1 + w2 + w3;
        }
        __syncthreads();
        #pragma unroll
        for (int kss = 0; kss < 2; ++kss) {
            bf16x8 a = *(const bf16x8*)&As[w * 16 + lr][kss * 32 + lk * 8];
            #pragma unroll
            for (int n = 0; n < 4; ++n) {
                bf16x8 b = *(const bf16x8*)&Bs[n * 16 + lr][kss * 32 + lk * 8];
                acc[n] = __builtin_amdgcn_mfma_f32_16x16x32_bf16(a, b, acc[n], 0, 0, 0);
            }
        }
        __syncthreads();
    }
#undef LOADC

    // row-sum: reduce across 16 lanes sharing a row, one atomic per row
    #pragma unroll
    for (int e = 0; e < 4; ++e) {
        float p = rs[e];
        p += __shfl_xor(p, 1, 64);
        p += __shfl_xor(p, 2, 64);
        p += __shfl_xor(p, 4, 64);
        p += __shfl_xor(p, 8, 64);
        int r = e * 16 + sr;
        if ((t & 15) == 0 && row0 + r < NN) atomicAdd(&S[row0 + r], p);
    }
    // C/D layout: col = lane&15, row = (lane>>4)*4 + reg
    #pragma unroll
    for (int n = 0; n < 4; ++n) {
        #pragma unroll
        for (int r = 0; r < 4; ++r) {
            int grow = row0 + w * 16 + lk * 4 + r;
            if (grow < NN)
                atomicAdd(&Num[(size_t)grow * FOUT + n * 16 + lr], acc[n][r]);
        }
    }
}

// ---------------- merged scatter: dw compute + Num/S update ----------------
__global__ __launch_bounds__(256) void k_scat2(const int* __restrict__ ep,
                                               const float* __restrict__ sums,
                                               const float* __restrict__ cnts,
                                               const unsigned* __restrict__ hkey,
                                               const unsigned* __restrict__ hprio,
                                               const float* __restrict__ adj,
                                               const float* __restrict__ seq,
                                               float* __restrict__ S,
                                               float* __restrict__ Num) {
    __shared__ float dws[256];
    __shared__ int   iis[256];
    __shared__ int   jjs[256];
    int t = threadIdx.x;
    int e = blockIdx.x * 256 + t;
    float dw = 0.f;
    int i = 0, j = 0;
    if (e < 2 * EE) {
        int k;
        entry_ij(ep, e, i, j, k);
        unsigned cell = (unsigned)i * NN + (unsigned)j;
        unsigned keyv = cell + 1u;
        unsigned h = hash_cell(cell);
        while (hkey[h] != keyv) h = (h + 1u) & HMASK;
        if (hprio[h] == (unsigned)(e + 1)) {   // last-write-wins winner
            float v   = sums[k] / fmaxf(cnts[k], 1.0f);
            float sg  = 1.f / (1.f + __expf(-v));
            float aij = adj[(size_t)i * NN + j];
            dw = __expf(aij + sg) - __expf(aij + 0.5f);
            if (dw != 0.f) atomicAdd(&S[i], dw);
        }
    }
    dws[t] = dw; iis[t] = i; jjs[t] = j;
    __syncthreads();
    int w = t >> 6, lane = t & 63;
    for (int q = 0; q < 64; ++q) {
        int idx = w * 64 + q;
        float d = dws[idx];                    // broadcast read
        if (d != 0.f) {
            atomicAdd(&Num[(size_t)iis[idx] * FOUT + lane],
                      d * seq[(size_t)jjs[idx] * FOUT + lane]);
        }
    }
}

// ---------------- finalize: elu(Num/S + bias) ----------------
__global__ void k_final(const float* __restrict__ Num,
                        const float* __restrict__ S,
                        const float* __restrict__ bias,
                        float* __restrict__ out) {
    int gid = blockIdx.x * 256 + threadIdx.x;
    if (gid >= NN * FOUT) return;
    int i = gid >> 6, c = gid & 63;
    float v = Num[gid] / S[i] + bias[c];
    out[gid] = (v > 0.f) ? v : expm1f(v);
}

extern "C" void kernel_launch(void* const* d_in, const int* in_sizes, int n_in,
                              void* d_out, int out_size, void* d_ws, size_t ws_size,
                              hipStream_t stream) {
    const float* x    = (const float*)d_in[0];
    const float* rel  = (const float*)d_in[1];
    const float* adj  = (const float*)d_in[2];
    const int*   ep   = (const int*)d_in[3];
    const int*   rseg = (const int*)d_in[4];
    const float* W    = (const float*)d_in[5];
    const float* wrel = (const float*)d_in[6];
    const float* bias = (const float*)d_in[7];
    float* out = (float*)d_out;

    float* ws = (float*)d_ws;
    float*    sums  = ws + O_SUMS;
    float*    cnts  = ws + O_CNTS;
    float*    S     = ws + O_S;
    float*    Num   = ws + O_NUM;
    unsigned* hkey  = (unsigned*)(ws + O_HKEY);
    unsigned* hprio = (unsigned*)(ws + O_HPRIO);
    __bf16*   seqT  = (__bf16*)(ws + O_SEQT);
    float*    seq   = ws + O_SEQ;

    int n4 = ZERO_WORDS / 4;   // ZERO_WORDS divisible by 4
    k_zero<<<(n4 + 255) / 256, 256, 0, stream>>>((f32x4*)d_ws, n4);

    k_seqfts<<<NN / 16, 256, 0, stream>>>(x, W, seq, seqT);
    k_scatA<<<(2 * EE + 255) / 256, 256, 0, stream>>>(ep, hkey, hprio);
    k_mainrel<<<MAINB + RELB, 256, 0, stream>>>(adj, seqT, rel, wrel, rseg,
                                                sums, cnts, Num, S);
    k_scat2<<<(2 * EE + 255) / 256, 256, 0, stream>>>(ep, sums, cnts, hkey, hprio,
                                                      adj, seq, S, Num);
    k_final<<<(NN * FOUT + 255) / 256, 256, 0, stream>>>(Num, S, bias, out);
}

// Round 6
// 264.862 us; speedup vs baseline: 2.0696x; 1.2605x over previous
//
#include <hip/hip_runtime.h>
#include <math.h>

#define NN   10000
#define EE   200000
#define RR   400000
#define FIN  128
#define FOUT 64
#define NK   10048           // 157*64, K padded for seqT

#define HASH_BITS 20
#define HSIZE (1u << HASH_BITS)
#define HMASK (HSIZE - 1u)
#define ROWCAP 256           // per-row edge slots (Binomial(400K,1e-4): P(>256)~0)

typedef __bf16 bf16x8 __attribute__((ext_vector_type(8)));
typedef __bf16 bf16x4 __attribute__((ext_vector_type(4)));
typedef float  f32x4  __attribute__((ext_vector_type(4)));

// ---- workspace layout (units of 4 bytes) ----
#define O_SUMS   0
#define O_CNTS   (O_SUMS + EE)
#define O_ROWCNT (O_CNTS + EE)             // int[NN]
#define O_HKEY   (O_ROWCNT + NN)
#define O_HPRIO  (O_HKEY + HSIZE)
#define O_SEQT   (O_HPRIO + HSIZE)         // bf16[64][NK] (pad cols must be 0)
#define ZERO_WORDS (O_SEQT + (FOUT * NK) / 2)   // 2,828,688 (div by 4)
#define O_SEQ    ZERO_WORDS                // f32[NN][64]
#define O_NUMP   (O_SEQ + NN * FOUT)       // f32[8][NN][64] partials
#define O_SP     (O_NUMP + 8 * NN * FOUT)  // f32[8][NN]
#define O_PAIRS  (O_SP + 8 * NN)           // uint2[NN][ROWCAP]

// ---------------- wide zero fill ----------------
__global__ __launch_bounds__(256) void k_zero(f32x4* __restrict__ p, int n4) {
    int gid = blockIdx.x * 256 + threadIdx.x;
    if (gid < n4) p[gid] = (f32x4){0.f, 0.f, 0.f, 0.f};
}

// ---------------- seq_fts = x @ W^T  (also emits bf16 transposed copy) ----
__global__ __launch_bounds__(256) void k_seqfts(const float* __restrict__ x,
                                                const float* __restrict__ W,
                                                float* __restrict__ seq,
                                                __bf16* __restrict__ seqT) {
    __shared__ float Wt[FIN][FOUT + 1];
    __shared__ float xs[FIN][16 + 1];
    int t = threadIdx.x;
    for (int e = t; e < FOUT * FIN; e += 256) {
        int c = e >> 7, k = e & 127;
        Wt[k][c] = W[e];
    }
    int row0 = blockIdx.x * 16;
    for (int e = t; e < 16 * FIN; e += 256) {
        int r = e >> 7, k = e & 127;
        int gr = row0 + r;
        xs[k][r] = (gr < NN) ? x[(size_t)gr * FIN + k] : 0.f;
    }
    __syncthreads();
    int col = t & 63;
    int rg  = t >> 6;
    float acc[4] = {0.f, 0.f, 0.f, 0.f};
    for (int k = 0; k < FIN; ++k) {
        float w = Wt[k][col];
        #pragma unroll
        for (int i = 0; i < 4; ++i) acc[i] += w * xs[k][rg * 4 + i];
    }
    #pragma unroll
    for (int i = 0; i < 4; ++i) {
        int gr = row0 + rg * 4 + i;
        if (gr < NN) {
            seq[(size_t)gr * FOUT + col] = acc[i];
            seqT[(size_t)col * NK + gr] = (__bf16)acc[i];
        }
    }
}

// ---------------- helpers ----------------
__device__ __forceinline__ unsigned hash_cell(unsigned cell) {
    return (cell * 2654435761u) >> (32 - HASH_BITS);
}
__device__ __forceinline__ void entry_ij(const int* ep, int e, int& i, int& j, int& k) {
    k = (e < EE) ? e : e - EE;
    int a = ep[2 * k], b = ep[2 * k + 1];
    if (e < EE) { i = a; j = b; } else { i = b; j = a; }
}

// ------- merged: main matmul (partials)  ||  rel segsum  ||  hash build -----
#define BM 64
#define BK 64
#define KSPLIT 8
#define NCHUNK 157
#define CPK ((NCHUNK + KSPLIT - 1) / KSPLIT)   // 20
#define MAINB (NCHUNK * KSPLIT)                // 1256
#define ILV   11                               // 1 main : 10 rel
#define MRB   (ILV * MAINB)                    // 13816 (12560 rel slots)
#define SCATAB ((2 * EE + 255) / 256)          // 1563
#define GRID_MR (MRB + SCATAB)
#define LDAP (BK + 8)

__global__ __launch_bounds__(256) void k_mainrel(const float* __restrict__ adj,
                                                 const __bf16* __restrict__ seqT,
                                                 const float* __restrict__ rel,
                                                 const float* __restrict__ wrel,
                                                 const int* __restrict__ rseg,
                                                 const int* __restrict__ ep,
                                                 float* __restrict__ sums,
                                                 float* __restrict__ cnts,
                                                 unsigned* __restrict__ hkey,
                                                 unsigned* __restrict__ hprio,
                                                 float* __restrict__ Nump,
                                                 float* __restrict__ Sp) {
    __shared__ __bf16 As[2][BM][LDAP];
    __shared__ __bf16 Bs[2][FOUT][LDAP];
    int t   = threadIdx.x;
    int bid = blockIdx.x;

    if (bid >= MRB) {
        // ---- hash-build role (runs in tail; must finish before k_scatB) ----
        int e = (bid - MRB) * 256 + t;
        if (e >= 2 * EE) return;
        int i, j, k;
        entry_ij(ep, e, i, j, k);
        unsigned cell = (unsigned)i * NN + (unsigned)j;
        unsigned keyv = cell + 1u;
        unsigned h = hash_cell(cell);
        while (true) {
            unsigned old = atomicCAS(&hkey[h], 0u, keyv);
            if (old == 0u || old == keyv) break;
            h = (h + 1u) & HMASK;
        }
        atomicMax(&hprio[h], (unsigned)(e + 1));
        return;
    }

    if (bid % ILV) {
        // ---- rel role: 32 rows per block, 32-lane group per row ----
        int relb = bid - bid / ILV - 1;        // [0, 12560)
        int lane = t & 31;
        f32x4 w = *(const f32x4*)(wrel + lane * 4);
        #pragma unroll
        for (int it = 0; it < 4; ++it) {
            int row = relb * 32 + it * 8 + (t >> 5);
            if (row < RR) {
                f32x4 v = __builtin_nontemporal_load(
                    (const f32x4*)(rel + (size_t)row * FIN + lane * 4));
                float s = v.x * w.x + v.y * w.y + v.z * w.z + v.w * w.w;
                #pragma unroll
                for (int off = 16; off >= 1; off >>= 1) s += __shfl_xor(s, off, 64);
                if (lane == 0) {
                    int seg = rseg[row];
                    atomicAdd(&sums[seg], s);
                    atomicAdd(&cnts[seg], 1.0f);
                }
            }
        }
        return;
    }

    // ---- main role ----
    int mi   = bid / ILV;          // [0, 1256)
    int rowc = mi % NCHUNK;
    int ks   = mi / NCHUNK;
    int row0 = rowc * BM;
    int c0   = ks * CPK;
    int c1   = min(NCHUNK, c0 + CPK);
    int w  = t >> 6, l = t & 63;
    int lr = l & 15, lk = l >> 4;
    int sr = t >> 4;               // A-stage row within 16-row strip
    int sk = (t & 15) * 4;         // A-stage col (float4)
    int bc = t >> 3;               // B-stage col 0..31 (+32)
    int bk = (t & 7) * 8;          // B-stage k (bf16x8)

    f32x4 acc[4];
    #pragma unroll
    for (int n = 0; n < 4; ++n) acc[n] = (f32x4){0.f, 0.f, 0.f, 0.f};
    float rs[4] = {0.f, 0.f, 0.f, 0.f};

    f32x4  pva[4];
    bf16x8 pvb0, pvb1;

#define LOADC(CH)                                                              \
    {                                                                          \
        int k0_ = (CH) * BK;                                                   \
        _Pragma("unroll")                                                      \
        for (int e2 = 0; e2 < 4; ++e2) {                                       \
            int gr = row0 + sr + e2 * 16;                                      \
            int gk = k0_ + sk;                                                 \
            bool ok = (gr < NN) && (gk < NN);                                  \
            pva[e2] = ok ? __builtin_nontemporal_load(                         \
                               (const f32x4*)(adj + (size_t)gr * NN + gk))     \
                         : (f32x4){0.f, 0.f, 0.f, 0.f};                        \
        }                                                                      \
        pvb0 = *(const bf16x8*)(seqT + (size_t)bc * NK + k0_ + bk);            \
        pvb1 = *(const bf16x8*)(seqT + (size_t)(bc + 32) * NK + k0_ + bk);     \
    }

    LOADC(c0);
    int p = 0;
    for (int ch = c0; ch < c1; ++ch) {
        // drain prefetch regs into LDS[p] (exp fused for A, row-sums in regs)
        *(bf16x8*)&Bs[p][bc][bk]      = pvb0;
        *(bf16x8*)&Bs[p][bc + 32][bk] = pvb1;
        bool okk = (ch * BK + sk < NN);
        #pragma unroll
        for (int e2 = 0; e2 < 4; ++e2) {
            bool ok = okk && (row0 + sr + e2 * 16 < NN);
            float w0 = ok ? __expf(pva[e2].x + 0.5f) : 0.f;
            float w1 = ok ? __expf(pva[e2].y + 0.5f) : 0.f;
            float w2 = ok ? __expf(pva[e2].z + 0.5f) : 0.f;
            float w3 = ok ? __expf(pva[e2].w + 0.5f) : 0.f;
            bf16x4 bv = { (__bf16)w0, (__bf16)w1, (__bf16)w2, (__bf16)w3 };
            *(bf16x4*)&As[p][sr + e2 * 16][sk] = bv;
            rs[e2] += w0 + w1 + w2 + w3;
        }
        if (ch + 1 < c1) LOADC(ch + 1);        // issue next-chunk loads
        __syncthreads();                        // LDS[p] ready (1 barrier/chunk)
        #pragma unroll
        for (int kss = 0; kss < 2; ++kss) {
            bf16x8 a = *(const bf16x8*)&As[p][w * 16 + lr][kss * 32 + lk * 8];
            #pragma unroll
            for (int n = 0; n < 4; ++n) {
                bf16x8 b = *(const bf16x8*)&Bs[p][n * 16 + lr][kss * 32 + lk * 8];
                acc[n] = __builtin_amdgcn_mfma_f32_16x16x32_bf16(a, b, acc[n], 0, 0, 0);
            }
        }
        p ^= 1;
    }
#undef LOADC

    // row-sum partials: reduce across the 16 lanes sharing a row, plain store
    #pragma unroll
    for (int e = 0; e < 4; ++e) {
        float pp = rs[e];
        pp += __shfl_xor(pp, 1, 64);
        pp += __shfl_xor(pp, 2, 64);
        pp += __shfl_xor(pp, 4, 64);
        pp += __shfl_xor(pp, 8, 64);
        int r = e * 16 + sr;
        if ((t & 15) == 0 && row0 + r < NN)
            Sp[(size_t)ks * NN + row0 + r] = pp;
    }
    // C/D layout: col = lane&15, row = (lane>>4)*4 + reg ; plain stores
    #pragma unroll
    for (int n = 0; n < 4; ++n) {
        #pragma unroll
        for (int r = 0; r < 4; ++r) {
            int grow = row0 + w * 16 + lk * 4 + r;
            if (grow < NN)
                Nump[(size_t)ks * NN * FOUT + (size_t)grow * FOUT + n * 16 + lr]
                    = acc[n][r];
        }
    }
}

// ------- scatB: winner check + dw compute + push (j,dw) into row bucket -----
__global__ __launch_bounds__(256) void k_scatB(const int* __restrict__ ep,
                                               const float* __restrict__ sums,
                                               const float* __restrict__ cnts,
                                               const unsigned* __restrict__ hkey,
                                               const unsigned* __restrict__ hprio,
                                               const float* __restrict__ adj,
                                               int* __restrict__ rowcnt,
                                               uint2* __restrict__ pairs) {
    int e = blockIdx.x * 256 + threadIdx.x;
    if (e >= 2 * EE) return;
    int i, j, k;
    entry_ij(ep, e, i, j, k);
    unsigned cell = (unsigned)i * NN + (unsigned)j;
    unsigned keyv = cell + 1u;
    unsigned h = hash_cell(cell);
    while (hkey[h] != keyv) h = (h + 1u) & HMASK;
    if (hprio[h] == (unsigned)(e + 1)) {   // last-write-wins winner
        float v   = sums[k] / fmaxf(cnts[k], 1.0f);
        float sg  = 1.f / (1.f + __expf(-v));
        float aij = adj[(size_t)i * NN + j];
        float dw  = __expf(aij + sg) - __expf(aij + 0.5f);
        if (dw != 0.f) {
            int pos = atomicAdd(&rowcnt[i], 1);
            if (pos < ROWCAP)
                pairs[(size_t)i * ROWCAP + pos] =
                    make_uint2((unsigned)j, __float_as_uint(dw));
        }
    }
}

// ------- rowupd: one wave per row: sum partials + edge corr + elu -> out ----
__global__ __launch_bounds__(256) void k_rowupd(const float* __restrict__ Nump,
                                                const float* __restrict__ Sp,
                                                const int* __restrict__ rowcnt,
                                                const uint2* __restrict__ pairs,
                                                const float* __restrict__ seq,
                                                const float* __restrict__ bias,
                                                float* __restrict__ out) {
    int t = threadIdx.x;
    int i = blockIdx.x * 4 + (t >> 6);
    if (i >= NN) return;
    int c = t & 63;
    float acc = 0.f, sb = 0.f;
    #pragma unroll
    for (int ks = 0; ks < 8; ++ks) {
        acc += Nump[(size_t)ks * NN * FOUT + (size_t)i * FOUT + c];
        sb  += Sp[(size_t)ks * NN + i];
    }
    int cnt = min(rowcnt[i], ROWCAP);
    float sdw = 0.f;
    const uint2* pr = pairs + (size_t)i * ROWCAP;
    #pragma unroll 4
    for (int e = 0; e < cnt; ++e) {
        uint2 pk = pr[e];                      // wave-uniform broadcast load
        float d  = __uint_as_float(pk.y);
        acc += d * seq[(size_t)pk.x * FOUT + c];
        sdw += d;
    }
    float v = acc / (sb + sdw) + bias[c];
    out[(size_t)i * FOUT + c] = (v > 0.f) ? v : expm1f(v);
}

extern "C" void kernel_launch(void* const* d_in, const int* in_sizes, int n_in,
                              void* d_out, int out_size, void* d_ws, size_t ws_size,
                              hipStream_t stream) {
    const float* x    = (const float*)d_in[0];
    const float* rel  = (const float*)d_in[1];
    const float* adj  = (const float*)d_in[2];
    const int*   ep   = (const int*)d_in[3];
    const int*   rseg = (const int*)d_in[4];
    const float* W    = (const float*)d_in[5];
    const float* wrel = (const float*)d_in[6];
    const float* bias = (const float*)d_in[7];
    float* out = (float*)d_out;

    float* ws = (float*)d_ws;
    float*    sums   = ws + O_SUMS;
    float*    cnts   = ws + O_CNTS;
    int*      rowcnt = (int*)(ws + O_ROWCNT);
    unsigned* hkey   = (unsigned*)(ws + O_HKEY);
    unsigned* hprio  = (unsigned*)(ws + O_HPRIO);
    __bf16*   seqT   = (__bf16*)(ws + O_SEQT);
    float*    seq    = ws + O_SEQ;
    float*    Nump   = ws + O_NUMP;
    float*    Sp     = ws + O_SP;
    uint2*    pairs  = (uint2*)(ws + O_PAIRS);

    int n4 = ZERO_WORDS / 4;
    k_zero<<<(n4 + 255) / 256, 256, 0, stream>>>((f32x4*)d_ws, n4);
    k_seqfts<<<NN / 16, 256, 0, stream>>>(x, W, seq, seqT);
    k_mainrel<<<GRID_MR, 256, 0, stream>>>(adj, seqT, rel, wrel, rseg, ep,
                                           sums, cnts, hkey, hprio, Nump, Sp);
    k_scatB<<<SCATAB, 256, 0, stream>>>(ep, sums, cnts, hkey, hprio, adj,
                                        rowcnt, pairs);
    k_rowupd<<<(NN + 3) / 4, 256, 0, stream>>>(Nump, Sp, rowcnt, pairs,
                                               seq, bias, out);
}